// Round 1
// baseline (1242.665 us; speedup 1.0000x reference)
//
#include <hip/hip_runtime.h>
#include <math.h>

constexpr int B = 2, N = 2048, D = 384, H = 8, Dh = 48;
constexpr int M = B * N;            // 4096 rows
constexpr float EPS = 1e-5f;

#define TILE 32

// C[M x Dout] = A[M x K] * W[Dout x K]^T   (W row-major, i.e. B-transposed GEMM)
__global__ __launch_bounds__(256) void gemm_bt(
    const float* __restrict__ A, const float* __restrict__ W,
    float* __restrict__ C, int K, int Dout) {
  __shared__ float As[TILE][TILE + 1];
  __shared__ float Ws[TILE][TILE + 1];
  const int tid = threadIdx.x;
  const int col = tid & 31;       // output col within tile
  const int rowg = tid >> 5;      // 0..7, each handles 4 rows
  const int brow = blockIdx.y * TILE;
  const int bcol = blockIdx.x * TILE;
  float acc[4] = {0.f, 0.f, 0.f, 0.f};
  for (int kt = 0; kt < K; kt += TILE) {
    __syncthreads();
#pragma unroll
    for (int i = 0; i < 4; ++i) {
      int e = tid + i * 256;
      int r = e >> 5, c = e & 31;
      As[r][c] = A[(size_t)(brow + r) * K + kt + c];
      Ws[r][c] = W[(size_t)(bcol + r) * K + kt + c];
    }
    __syncthreads();
#pragma unroll
    for (int k = 0; k < TILE; ++k) {
      float w = Ws[col][k];
#pragma unroll
      for (int i = 0; i < 4; ++i)
        acc[i] += As[rowg * 4 + i][k] * w;
    }
  }
#pragma unroll
  for (int i = 0; i < 4; ++i)
    C[(size_t)(brow + rowg * 4 + i) * Dout + bcol + col] = acc[i];
}

// In-place rotate each 3-vector chunk of Q and K by the node's frame.
__global__ __launch_bounds__(256) void rotate_qk(
    float* __restrict__ Q, float* __restrict__ Kk, const float* __restrict__ F) {
  constexpr int GPH = Dh / 3;                 // 16 groups per head
  constexpr int total = B * N * H * GPH;      // per matrix
  int idx = blockIdx.x * 256 + threadIdx.x;
  if (idx >= 2 * total) return;
  float* T = (idx < total) ? Q : Kk;
  int rem = (idx < total) ? idx : idx - total;
  int g = rem % GPH;
  int nh = rem / GPH;       // (b*N+n)*H + h
  int h = nh % H;
  int bn = nh / H;          // b*N + n
  size_t off = (size_t)bn * D + h * Dh + g * 3;
  const float* R = F + (size_t)bn * 9;
  float v0 = T[off], v1 = T[off + 1], v2 = T[off + 2];
  T[off]     = R[0] * v0 + R[1] * v1 + R[2] * v2;
  T[off + 1] = R[3] * v0 + R[4] * v1 + R[5] * v2;
  T[off + 2] = R[6] * v0 + R[7] * v1 + R[8] * v2;
}

// Flash-style attention: one thread per query row; K/V tiles staged in LDS.
// Out may alias Qr (each block reads only its own Q rows into registers first).
__global__ __launch_bounds__(256) void attn_fwd(
    const float* __restrict__ Qr, const float* __restrict__ Kr,
    const float* __restrict__ V, float* __restrict__ Out) {
  constexpr int QT = 256, TK = 64;
  constexpr int nqt = N / QT;     // 8
  const int bid = blockIdx.x;
  const int qt = bid % nqt;
  const int h = (bid / nqt) % H;
  const int b = bid / (nqt * H);
  const int q = qt * QT + threadIdx.x;
  __shared__ float Ks[TK][Dh];
  __shared__ float Vs[TK][Dh];
  const float scale = 0.14433756729740643f;  // 1/sqrt(48)
  float qv[Dh];
  {
    const float* qp = Qr + (size_t)(b * N + q) * D + h * Dh;
#pragma unroll
    for (int j = 0; j < Dh; ++j) qv[j] = qp[j] * scale;
  }
  float m = -3.0e38f, l = 0.f;
  float acc[Dh];
#pragma unroll
  for (int j = 0; j < Dh; ++j) acc[j] = 0.f;

  for (int kt = 0; kt < N; kt += TK) {
    __syncthreads();
    for (int e = threadIdx.x; e < TK * Dh; e += QT) {
      int kk = e / Dh, j = e - kk * Dh;
      size_t src = (size_t)(b * N + kt + kk) * D + h * Dh + j;
      Ks[kk][j] = Kr[src];
      Vs[kk][j] = V[src];
    }
    __syncthreads();
    for (int kk = 0; kk < TK; ++kk) {
      float s0 = 0.f, s1 = 0.f, s2 = 0.f, s3 = 0.f;
#pragma unroll
      for (int j = 0; j < Dh; j += 4) {
        s0 += qv[j]     * Ks[kk][j];
        s1 += qv[j + 1] * Ks[kk][j + 1];
        s2 += qv[j + 2] * Ks[kk][j + 2];
        s3 += qv[j + 3] * Ks[kk][j + 3];
      }
      float s = (s0 + s1) + (s2 + s3);
      if (s > m) {
        float corr = __expf(m - s);
        l *= corr;
#pragma unroll
        for (int j = 0; j < Dh; ++j) acc[j] *= corr;
        m = s;
      }
      float p = __expf(s - m);
      l += p;
#pragma unroll
      for (int j = 0; j < Dh; ++j) acc[j] += p * Vs[kk][j];
    }
  }
  float inv = 1.f / l;
  float* op = Out + (size_t)(b * N + q) * D + h * Dh;
#pragma unroll
  for (int j = 0; j < Dh; ++j) op[j] = acc[j] * inv;
}

// y = x + O + bo; LayerNorm(y) * gamma + beta  -> out.  One block per row.
__global__ __launch_bounds__(384) void resid_ln(
    const float* __restrict__ x, const float* __restrict__ O,
    const float* __restrict__ bo, const float* __restrict__ gamma,
    const float* __restrict__ beta, float* __restrict__ out) {
  __shared__ float rs[6], rs2[6];
  __shared__ float smu, srstd;
  const int row = blockIdx.x;
  const int d = threadIdx.x;
  const size_t off = (size_t)row * D + d;
  float y = x[off] + O[off] + bo[d];
  float s = y, s2 = y * y;
#pragma unroll
  for (int o = 1; o < 64; o <<= 1) {
    s += __shfl_xor(s, o);
    s2 += __shfl_xor(s2, o);
  }
  const int wave = d >> 6, lane = d & 63;
  if (lane == 0) { rs[wave] = s; rs2[wave] = s2; }
  __syncthreads();
  if (d == 0) {
    float ts = 0.f, ts2 = 0.f;
#pragma unroll
    for (int w = 0; w < 6; ++w) { ts += rs[w]; ts2 += rs2[w]; }
    float mu = ts / (float)D;
    float var = ts2 / (float)D - mu * mu;
    smu = mu;
    srstd = rsqrtf(var + EPS);
  }
  __syncthreads();
  out[off] = (y - smu) * srstd * gamma[d] + beta[d];
}

extern "C" void kernel_launch(void* const* d_in, const int* in_sizes, int n_in,
                              void* d_out, int out_size, void* d_ws, size_t ws_size,
                              hipStream_t stream) {
  const float* x      = (const float*)d_in[0];
  const float* frames = (const float*)d_in[1];
  const float* Wq     = (const float*)d_in[2];
  const float* Wk     = (const float*)d_in[3];
  const float* Wv     = (const float*)d_in[4];
  const float* Wo     = (const float*)d_in[5];
  const float* bo     = (const float*)d_in[6];
  const float* gamma  = (const float*)d_in[7];
  const float* beta   = (const float*)d_in[8];
  float* out = (float*)d_out;

  float* Qb = (float*)d_ws;
  float* Kb = Qb + (size_t)M * D;
  float* Vb = Kb + (size_t)M * D;

  dim3 ggrid(D / TILE, M / TILE);  // (12, 128)
  gemm_bt<<<ggrid, 256, 0, stream>>>(x, Wq, Qb, D, D);
  gemm_bt<<<ggrid, 256, 0, stream>>>(x, Wk, Kb, D, D);
  gemm_bt<<<ggrid, 256, 0, stream>>>(x, Wv, Vb, D, D);

  constexpr int nrot = 2 * B * N * H * (Dh / 3);
  rotate_qk<<<(nrot + 255) / 256, 256, 0, stream>>>(Qb, Kb, frames);

  attn_fwd<<<B * H * (N / 256), 256, 0, stream>>>(Qb, Kb, Vb, Qb);

  gemm_bt<<<ggrid, 256, 0, stream>>>(Qb, Wo, Kb, D, D);

  resid_ln<<<M, D, 0, stream>>>(x, Kb, bo, gamma, beta, out);
}

// Round 2
// 666.117 us; speedup vs baseline: 1.8655x; 1.8655x over previous
//
#include <hip/hip_runtime.h>
#include <math.h>

constexpr int B = 2, N = 2048, D = 384, H = 8, Dh = 48;
constexpr int M = B * N;            // 4096 rows
constexpr float EPS = 1e-5f;

#define TILE 32

// C[M x Dout] = A[M x K] * W[Dout x K]^T   (W row-major, i.e. B-transposed GEMM)
__global__ __launch_bounds__(256) void gemm_bt(
    const float* __restrict__ A, const float* __restrict__ W,
    float* __restrict__ C, int K, int Dout) {
  __shared__ float As[TILE][TILE + 1];
  __shared__ float Ws[TILE][TILE + 1];
  const int tid = threadIdx.x;
  const int col = tid & 31;       // output col within tile
  const int rowg = tid >> 5;      // 0..7, each handles 4 rows
  const int brow = blockIdx.y * TILE;
  const int bcol = blockIdx.x * TILE;
  float acc[4] = {0.f, 0.f, 0.f, 0.f};
  for (int kt = 0; kt < K; kt += TILE) {
    __syncthreads();
#pragma unroll
    for (int i = 0; i < 4; ++i) {
      int e = tid + i * 256;
      int r = e >> 5, c = e & 31;
      As[r][c] = A[(size_t)(brow + r) * K + kt + c];
      Ws[r][c] = W[(size_t)(bcol + r) * K + kt + c];
    }
    __syncthreads();
#pragma unroll
    for (int k = 0; k < TILE; ++k) {
      float w = Ws[col][k];
#pragma unroll
      for (int i = 0; i < 4; ++i)
        acc[i] += As[rowg * 4 + i][k] * w;
    }
  }
#pragma unroll
  for (int i = 0; i < 4; ++i)
    C[(size_t)(brow + rowg * 4 + i) * Dout + bcol + col] = acc[i];
}

// In-place rotate each 3-vector chunk of Q and K by the node's frame.
__global__ __launch_bounds__(256) void rotate_qk(
    float* __restrict__ Q, float* __restrict__ Kk, const float* __restrict__ F) {
  constexpr int GPH = Dh / 3;                 // 16 groups per head
  constexpr int total = B * N * H * GPH;      // per matrix
  int idx = blockIdx.x * 256 + threadIdx.x;
  if (idx >= 2 * total) return;
  float* T = (idx < total) ? Q : Kk;
  int rem = (idx < total) ? idx : idx - total;
  int g = rem % GPH;
  int nh = rem / GPH;       // (b*N+n)*H + h
  int h = nh % H;
  int bn = nh / H;          // b*N + n
  size_t off = (size_t)bn * D + h * Dh + g * 3;
  const float* R = F + (size_t)bn * 9;
  float v0 = T[off], v1 = T[off + 1], v2 = T[off + 2];
  T[off]     = R[0] * v0 + R[1] * v1 + R[2] * v2;
  T[off + 1] = R[3] * v0 + R[4] * v1 + R[5] * v2;
  T[off + 2] = R[6] * v0 + R[7] * v1 + R[8] * v2;
}

// Flash-style attention, 4 threads per query (12 dims each, float4-vectorized).
// 64 queries per block, 128-key LDS tiles. Out may alias Qr (disjoint columns
// per head; own Q read into registers before any write).
__global__ __launch_bounds__(256) void attn_fwd(
    const float* __restrict__ Qr, const float* __restrict__ Kr,
    const float* __restrict__ V, float* __restrict__ Out) {
  constexpr int QT = 64, TK = 128;
  constexpr int nqt = N / QT;        // 32
  constexpr int ROWF4 = Dh / 4;      // 12 float4 per row
  const int bid = blockIdx.x;
  const int qt = bid % nqt;
  const int h = (bid / nqt) % H;
  const int b = bid / (nqt * H);
  const int tid = threadIdx.x;
  const int ql = tid >> 2;           // local query 0..63
  const int ch = tid & 3;            // dim chunk 0..3 (12 floats each)
  const int q = qt * QT + ql;
  __shared__ float Ks[TK * Dh];
  __shared__ float Vs[TK * Dh];
  const float scale = 0.14433756729740643f;  // 1/sqrt(48)

  float4 qv[3];
  {
    const float4* qp =
        (const float4*)(Qr + (size_t)(b * N + q) * D + h * Dh + ch * 12);
#pragma unroll
    for (int j = 0; j < 3; ++j) {
      float4 t = qp[j];
      qv[j] = make_float4(t.x * scale, t.y * scale, t.z * scale, t.w * scale);
    }
  }
  float m = -3.0e38f, l = 0.f;
  float4 acc[3];
#pragma unroll
  for (int j = 0; j < 3; ++j) acc[j] = make_float4(0.f, 0.f, 0.f, 0.f);

  for (int kt = 0; kt < N; kt += TK) {
    __syncthreads();
    for (int e = tid; e < TK * ROWF4; e += 256) {
      int kk = e / ROWF4, j = e - kk * ROWF4;
      size_t base = (size_t)(b * N + kt + kk) * D + h * Dh;
      ((float4*)Ks)[e] = *((const float4*)(Kr + base) + j);
      ((float4*)Vs)[e] = *((const float4*)(V + base) + j);
    }
    __syncthreads();
#pragma unroll 4
    for (int kk = 0; kk < TK; ++kk) {
      const float4* kp = (const float4*)Ks + kk * ROWF4 + ch * 3;
      float s = 0.f;
#pragma unroll
      for (int j = 0; j < 3; ++j) {
        float4 kv = kp[j];
        s += qv[j].x * kv.x + qv[j].y * kv.y + qv[j].z * kv.z + qv[j].w * kv.w;
      }
      s += __shfl_xor(s, 1);
      s += __shfl_xor(s, 2);
      if (s > m) {
        float corr = __expf(m - s);
        l *= corr;
#pragma unroll
        for (int j = 0; j < 3; ++j) {
          acc[j].x *= corr; acc[j].y *= corr;
          acc[j].z *= corr; acc[j].w *= corr;
        }
        m = s;
      }
      float p = __expf(s - m);
      l += p;
      const float4* vp = (const float4*)Vs + kk * ROWF4 + ch * 3;
#pragma unroll
      for (int j = 0; j < 3; ++j) {
        float4 vv = vp[j];
        acc[j].x += p * vv.x; acc[j].y += p * vv.y;
        acc[j].z += p * vv.z; acc[j].w += p * vv.w;
      }
    }
  }
  float inv = 1.f / l;
  float4* op = (float4*)(Out + (size_t)(b * N + q) * D + h * Dh + ch * 12);
#pragma unroll
  for (int j = 0; j < 3; ++j)
    op[j] = make_float4(acc[j].x * inv, acc[j].y * inv,
                        acc[j].z * inv, acc[j].w * inv);
}

// y = x + O + bo; LayerNorm(y) * gamma + beta  -> out.  One block per row.
__global__ __launch_bounds__(384) void resid_ln(
    const float* __restrict__ x, const float* __restrict__ O,
    const float* __restrict__ bo, const float* __restrict__ gamma,
    const float* __restrict__ beta, float* __restrict__ out) {
  __shared__ float rs[6], rs2[6];
  __shared__ float smu, srstd;
  const int row = blockIdx.x;
  const int d = threadIdx.x;
  const size_t off = (size_t)row * D + d;
  float y = x[off] + O[off] + bo[d];
  float s = y, s2 = y * y;
#pragma unroll
  for (int o = 1; o < 64; o <<= 1) {
    s += __shfl_xor(s, o);
    s2 += __shfl_xor(s2, o);
  }
  const int wave = d >> 6, lane = d & 63;
  if (lane == 0) { rs[wave] = s; rs2[wave] = s2; }
  __syncthreads();
  if (d == 0) {
    float ts = 0.f, ts2 = 0.f;
#pragma unroll
    for (int w = 0; w < 6; ++w) { ts += rs[w]; ts2 += rs2[w]; }
    float mu = ts / (float)D;
    float var = ts2 / (float)D - mu * mu;
    smu = mu;
    srstd = rsqrtf(var + EPS);
  }
  __syncthreads();
  out[off] = (y - smu) * srstd * gamma[d] + beta[d];
}

extern "C" void kernel_launch(void* const* d_in, const int* in_sizes, int n_in,
                              void* d_out, int out_size, void* d_ws, size_t ws_size,
                              hipStream_t stream) {
  const float* x      = (const float*)d_in[0];
  const float* frames = (const float*)d_in[1];
  const float* Wq     = (const float*)d_in[2];
  const float* Wk     = (const float*)d_in[3];
  const float* Wv     = (const float*)d_in[4];
  const float* Wo     = (const float*)d_in[5];
  const float* bo     = (const float*)d_in[6];
  const float* gamma  = (const float*)d_in[7];
  const float* beta   = (const float*)d_in[8];
  float* out = (float*)d_out;

  float* Qb = (float*)d_ws;
  float* Kb = Qb + (size_t)M * D;
  float* Vb = Kb + (size_t)M * D;

  dim3 ggrid(D / TILE, M / TILE);  // (12, 128)
  gemm_bt<<<ggrid, 256, 0, stream>>>(x, Wq, Qb, D, D);
  gemm_bt<<<ggrid, 256, 0, stream>>>(x, Wk, Kb, D, D);
  gemm_bt<<<ggrid, 256, 0, stream>>>(x, Wv, Vb, D, D);

  constexpr int nrot = 2 * B * N * H * (Dh / 3);
  rotate_qk<<<(nrot + 255) / 256, 256, 0, stream>>>(Qb, Kb, frames);

  attn_fwd<<<B * H * (N / 64), 256, 0, stream>>>(Qb, Kb, Vb, Qb);

  gemm_bt<<<ggrid, 256, 0, stream>>>(Qb, Wo, Kb, D, D);

  resid_ln<<<M, D, 0, stream>>>(x, Kb, bo, gamma, beta, out);
}

// Round 3
// 297.740 us; speedup vs baseline: 4.1737x; 2.2372x over previous
//
#include <hip/hip_runtime.h>
#include <math.h>

constexpr int B = 2, N = 2048, D = 384, H = 8, Dh = 48;
constexpr int M = B * N;            // 4096 rows
constexpr float EPS = 1e-5f;

typedef short bf16x8 __attribute__((ext_vector_type(8)));
typedef float f32x4 __attribute__((ext_vector_type(4)));

__device__ __forceinline__ ushort f2bf(float f) {
  union { float f; uint u; } v; v.f = f;
  uint r = v.u + 0x7fffu + ((v.u >> 16) & 1u);   // RNE
  return (ushort)(r >> 16);
}

#define TILE 32

// C[M x Dout] = A[M x K] * W[Dout x K]^T   (f32 VALU GEMM)
__global__ __launch_bounds__(256) void gemm_bt(
    const float* __restrict__ A, const float* __restrict__ W,
    float* __restrict__ C, int K, int Dout) {
  __shared__ float As[TILE][TILE + 1];
  __shared__ float Ws[TILE][TILE + 1];
  const int tid = threadIdx.x;
  const int col = tid & 31;
  const int rowg = tid >> 5;
  const int brow = blockIdx.y * TILE;
  const int bcol = blockIdx.x * TILE;
  float acc[4] = {0.f, 0.f, 0.f, 0.f};
  for (int kt = 0; kt < K; kt += TILE) {
    __syncthreads();
#pragma unroll
    for (int i = 0; i < 4; ++i) {
      int e = tid + i * 256;
      int r = e >> 5, c = e & 31;
      As[r][c] = A[(size_t)(brow + r) * K + kt + c];
      Ws[r][c] = W[(size_t)(bcol + r) * K + kt + c];
    }
    __syncthreads();
#pragma unroll
    for (int k = 0; k < TILE; ++k) {
      float w = Ws[col][k];
#pragma unroll
      for (int i = 0; i < 4; ++i)
        acc[i] += As[rowg * 4 + i][k] * w;
    }
  }
#pragma unroll
  for (int i = 0; i < 4; ++i)
    C[(size_t)(brow + rowg * 4 + i) * Dout + bcol + col] = acc[i];
}

// Same GEMM, but epilogue writes bf16 V^T laid out [B][H][Dh][N].
__global__ __launch_bounds__(256) void gemm_bt_vt(
    const float* __restrict__ A, const float* __restrict__ W,
    ushort* __restrict__ Vt) {
  __shared__ float As[TILE][TILE + 1];
  __shared__ float Ws[TILE][TILE + 1];
  const int tid = threadIdx.x;
  const int col = tid & 31;
  const int rowg = tid >> 5;
  const int brow = blockIdx.y * TILE;
  const int bcol = blockIdx.x * TILE;
  float acc[4] = {0.f, 0.f, 0.f, 0.f};
  for (int kt = 0; kt < D; kt += TILE) {
    __syncthreads();
#pragma unroll
    for (int i = 0; i < 4; ++i) {
      int e = tid + i * 256;
      int r = e >> 5, c = e & 31;
      As[r][c] = A[(size_t)(brow + r) * D + kt + c];
      Ws[r][c] = W[(size_t)(bcol + r) * D + kt + c];
    }
    __syncthreads();
#pragma unroll
    for (int k = 0; k < TILE; ++k) {
      float w = Ws[col][k];
#pragma unroll
      for (int i = 0; i < 4; ++i)
        acc[i] += As[rowg * 4 + i][k] * w;
    }
  }
  const int colD = bcol + col;
  const int hh = colD / 48;
  const int dh = colD - hh * 48;
  const int r0 = brow + rowg * 4;
  const int bb = r0 >> 11;
  const int nn = r0 & 2047;
  ushort u0 = f2bf(acc[0]), u1 = f2bf(acc[1]);
  ushort u2 = f2bf(acc[2]), u3 = f2bf(acc[3]);
  uint2 pk;
  pk.x = (uint)u0 | ((uint)u1 << 16);
  pk.y = (uint)u2 | ((uint)u3 << 16);
  *(uint2*)&Vt[((size_t)(bb * H + hh) * 48 + dh) * (size_t)N + nn] = pk;
}

// Rotate each 3-vector chunk by the node's frame, scale, pack to bf16.
__global__ __launch_bounds__(256) void rotate_pack(
    const float* __restrict__ src, const float* __restrict__ F,
    ushort* __restrict__ dst, float scale) {
  int idx = blockIdx.x * 256 + threadIdx.x;     // B*N*H*16
  int gq = idx & 15;
  int nh = idx >> 4;
  int h = nh & 7;
  int bn = nh >> 3;
  size_t off = (size_t)bn * D + h * 48 + gq * 3;
  const float* R = F + (size_t)bn * 9;
  float v0 = src[off], v1 = src[off + 1], v2 = src[off + 2];
  float w0 = (R[0] * v0 + R[1] * v1 + R[2] * v2) * scale;
  float w1 = (R[3] * v0 + R[4] * v1 + R[5] * v2) * scale;
  float w2 = (R[6] * v0 + R[7] * v1 + R[8] * v2) * scale;
  dst[off] = f2bf(w0);
  dst[off + 1] = f2bf(w1);
  dst[off + 2] = f2bf(w2);
}

// MFMA flash attention. Per block: one (b,h), 64 q rows (4 waves x 16).
// Swapped QK^T (S^T = K*Q) -> in-register softmax -> P via per-wave LDS -> PV.
__global__ __launch_bounds__(256) void attn_mfma(
    const ushort* __restrict__ Qbf, const ushort* __restrict__ Kbf,
    const ushort* __restrict__ Vt, float* __restrict__ O) {
  __shared__ ushort K_lds[64][72];      // [key][dh padded 64->72], cols 48..63 zero
  __shared__ ushort V_lds[48][72];      // [dh][key padded]
  __shared__ ushort P_lds[4][16][72];   // per-wave [q][key padded]

  const int wg = (blockIdx.x & 7) * 64 + (blockIdx.x >> 3);  // XCD swizzle (512%8==0)
  const int qt = wg & 31;
  const int h = (wg >> 5) & 7;
  const int b = wg >> 8;
  const int tid = threadIdx.x;
  const int w = tid >> 6;
  const int lane = tid & 63;
  const int lq = lane & 15;
  const int g = lane >> 4;

  if (tid < 128) {               // zero K-dim padding (read by MFMA)
    int row = tid >> 1, c = tid & 1;
    *(uint4*)&K_lds[row][48 + c * 8] = make_uint4(0, 0, 0, 0);
  }

  // Q fragments in registers (pre-scaled by 1/sqrt(48) at pack time)
  bf16x8 qf0, qf1;
  {
    const ushort* qp = Qbf + (size_t)(b * N + qt * 64 + w * 16 + lq) * D + h * 48;
    qf0 = *(const bf16x8*)(qp + g * 8);
    if (g < 2) {
      qf1 = *(const bf16x8*)(qp + 32 + g * 8);
    } else {
      bf16x8 z = {0, 0, 0, 0, 0, 0, 0, 0};
      qf1 = z;
    }
  }

  float m = -3.0e38f, l = 0.f;
  f32x4 oacc[3];
#pragma unroll
  for (int d = 0; d < 3; ++d) oacc[d] = f32x4{0.f, 0.f, 0.f, 0.f};

  for (int kt = 0; kt < N; kt += 64) {
    __syncthreads();
    for (int e = tid; e < 384; e += 256) {        // K tile: 64 rows x 48 halves
      int row = e / 6, c = e - row * 6;
      *(uint4*)&K_lds[row][c * 8] =
          *(const uint4*)(Kbf + (size_t)(b * N + kt + row) * D + h * 48 + c * 8);
    }
    for (int e = tid; e < 384; e += 256) {        // V^T tile: 48 rows x 64 halves
      int row = e >> 3, c = e & 7;
      *(uint4*)&V_lds[row][c * 8] =
          *(const uint4*)(Vt + ((size_t)(b * H + h) * 48 + row) * (size_t)N + kt + c * 8);
    }
    __syncthreads();

    // S^T[key, q] = K * Q : A-frag rows = keys, B-frag cols = q
    f32x4 st[4];
#pragma unroll
    for (int t = 0; t < 4; ++t) st[t] = f32x4{0.f, 0.f, 0.f, 0.f};
#pragma unroll
    for (int t = 0; t < 4; ++t) {
      bf16x8 a0 = *(const bf16x8*)&K_lds[t * 16 + lq][g * 8];
      st[t] = __builtin_amdgcn_mfma_f32_16x16x32_bf16(a0, qf0, st[t], 0, 0, 0);
      bf16x8 a1 = *(const bf16x8*)&K_lds[t * 16 + lq][32 + g * 8];
      st[t] = __builtin_amdgcn_mfma_f32_16x16x32_bf16(a1, qf1, st[t], 0, 0, 0);
    }

    // online softmax for q = lq (keys split: 16 in-reg, 4 lanes per q)
    float tmax = st[0][0];
#pragma unroll
    for (int t = 0; t < 4; ++t)
#pragma unroll
      for (int r = 0; r < 4; ++r) tmax = fmaxf(tmax, st[t][r]);
    tmax = fmaxf(tmax, __shfl_xor(tmax, 16));
    tmax = fmaxf(tmax, __shfl_xor(tmax, 32));
    float mnew = fmaxf(m, tmax);
    float corr = __expf(m - mnew);
    m = mnew;
    float psum = 0.f;
#pragma unroll
    for (int t = 0; t < 4; ++t) {
      ushort pb[4];
#pragma unroll
      for (int r = 0; r < 4; ++r) {
        float p = __expf(st[t][r] - mnew);
        psum += p;
        pb[r] = f2bf(p);
      }
      uint2 pk;
      pk.x = (uint)pb[0] | ((uint)pb[1] << 16);
      pk.y = (uint)pb[2] | ((uint)pb[3] << 16);
      *(uint2*)&P_lds[w][lq][t * 16 + g * 4] = pk;   // keys t*16+g*4..+3
    }
    psum += __shfl_xor(psum, 16);
    psum += __shfl_xor(psum, 32);
    l = l * corr + psum;

    // rescale O accumulator (rows q = g*4+r in O layout)
#pragma unroll
    for (int r = 0; r < 4; ++r) {
      float cr = __shfl(corr, g * 4 + r);
#pragma unroll
      for (int d = 0; d < 3; ++d) oacc[d][r] *= cr;
    }

    // PV: O[q,d] += P[q,keys] * V^T-frag
#pragma unroll
    for (int ks = 0; ks < 2; ++ks) {
      bf16x8 pf = *(const bf16x8*)&P_lds[w][lq][ks * 32 + g * 8];
#pragma unroll
      for (int d = 0; d < 3; ++d) {
        bf16x8 vf = *(const bf16x8*)&V_lds[d * 16 + lq][ks * 32 + g * 8];
        oacc[d] = __builtin_amdgcn_mfma_f32_16x16x32_bf16(pf, vf, oacc[d], 0, 0, 0);
      }
    }
  }

  float linv = 1.f / l;
  float lr[4];
#pragma unroll
  for (int r = 0; r < 4; ++r) lr[r] = __shfl(linv, g * 4 + r);
#pragma unroll
  for (int d = 0; d < 3; ++d)
#pragma unroll
    for (int r = 0; r < 4; ++r)
      O[(size_t)(b * N + qt * 64 + w * 16 + g * 4 + r) * D + h * 48 + d * 16 + lq] =
          oacc[d][r] * lr[r];
}

// y = x + O + bo; LayerNorm(y)*gamma + beta -> out. One block per row. O may alias out.
__global__ __launch_bounds__(384) void resid_ln(
    const float* __restrict__ x, const float* __restrict__ O,
    const float* __restrict__ bo, const float* __restrict__ gamma,
    const float* __restrict__ beta, float* __restrict__ out) {
  __shared__ float rs[6], rs2[6];
  __shared__ float smu, srstd;
  const int row = blockIdx.x;
  const int d = threadIdx.x;
  const size_t off = (size_t)row * D + d;
  float y = x[off] + O[off] + bo[d];
  float s = y, s2 = y * y;
#pragma unroll
  for (int o = 1; o < 64; o <<= 1) {
    s += __shfl_xor(s, o);
    s2 += __shfl_xor(s2, o);
  }
  const int wave = d >> 6, lane = d & 63;
  if (lane == 0) { rs[wave] = s; rs2[wave] = s2; }
  __syncthreads();
  if (d == 0) {
    float ts = 0.f, ts2 = 0.f;
#pragma unroll
    for (int wv = 0; wv < 6; ++wv) { ts += rs[wv]; ts2 += rs2[wv]; }
    float mu = ts / (float)D;
    float var = ts2 / (float)D - mu * mu;
    smu = mu;
    srstd = rsqrtf(var + EPS);
  }
  __syncthreads();
  out[off] = (y - smu) * srstd * gamma[d] + beta[d];
}

extern "C" void kernel_launch(void* const* d_in, const int* in_sizes, int n_in,
                              void* d_out, int out_size, void* d_ws, size_t ws_size,
                              hipStream_t stream) {
  const float* x      = (const float*)d_in[0];
  const float* frames = (const float*)d_in[1];
  const float* Wq     = (const float*)d_in[2];
  const float* Wk     = (const float*)d_in[3];
  const float* Wv     = (const float*)d_in[4];
  const float* Wo     = (const float*)d_in[5];
  const float* bo     = (const float*)d_in[6];
  const float* gamma  = (const float*)d_in[7];
  const float* beta   = (const float*)d_in[8];
  float* out = (float*)d_out;

  float* Qb   = (float*)d_ws;                     // M*D f32 (scratch, reused)
  ushort* Qbf = (ushort*)(Qb + (size_t)M * D);    // M*D bf16
  ushort* Kbf = Qbf + (size_t)M * D;
  ushort* Vtb = Kbf + (size_t)M * D;              // [B][H][48][N] bf16

  dim3 ggrid(D / TILE, M / TILE);  // (12, 128)
  const float qscale = 0.14433756729740643f;  // 1/sqrt(48)

  gemm_bt<<<ggrid, 256, 0, stream>>>(x, Wq, Qb, D, D);
  rotate_pack<<<M * H * 16 / 256, 256, 0, stream>>>(Qb, frames, Qbf, qscale);
  gemm_bt<<<ggrid, 256, 0, stream>>>(x, Wk, Qb, D, D);
  rotate_pack<<<M * H * 16 / 256, 256, 0, stream>>>(Qb, frames, Kbf, 1.0f);
  gemm_bt_vt<<<ggrid, 256, 0, stream>>>(x, Wv, Vtb);

  attn_mfma<<<B * H * (N / 64), 256, 0, stream>>>(Qbf, Kbf, Vtb, Qb);

  gemm_bt<<<ggrid, 256, 0, stream>>>(Qb, Wo, out, D, D);
  resid_ln<<<M, D, 0, stream>>>(x, out, bo, gamma, beta, out);
}

// Round 4
// 121.509 us; speedup vs baseline: 10.2270x; 2.4504x over previous
//
#include <hip/hip_runtime.h>
#include <math.h>

constexpr int B = 2, N = 2048, D = 384, H = 8, Dh = 48;
constexpr int M = B * N;            // 4096 rows
constexpr float EPS = 1e-5f;

typedef short bf16x8 __attribute__((ext_vector_type(8)));
typedef float f32x4 __attribute__((ext_vector_type(4)));

__device__ __forceinline__ ushort f2bf(float f) {
  union { float f; uint u; } v; v.f = f;
  uint r = v.u + 0x7fffu + ((v.u >> 16) & 1u);   // RNE
  return (ushort)(r >> 16);
}
__device__ __forceinline__ float bf2f(ushort u) {
  union { uint u; float f; } v; v.u = ((uint)u) << 16;
  return v.f;
}

// async 16B global->LDS (dest: wave-uniform base + lane*16; src: per-lane)
__device__ __forceinline__ void gload16(const void* g, void* lds) {
  __builtin_amdgcn_global_load_lds(
      (const __attribute__((address_space(1))) unsigned int*)g,
      (__attribute__((address_space(3))) unsigned int*)lds, 16, 0, 0);
}

// f32 -> bf16 pack, 8 elements per thread
__global__ __launch_bounds__(256) void pack_bf16(
    const float* __restrict__ src, ushort* __restrict__ dst) {
  int i = (blockIdx.x * 256 + threadIdx.x) * 8;
  float4 a = *(const float4*)(src + i);
  float4 b = *(const float4*)(src + i + 4);
  uint4 o;
  o.x = (uint)f2bf(a.x) | ((uint)f2bf(a.y) << 16);
  o.y = (uint)f2bf(a.z) | ((uint)f2bf(a.w) << 16);
  o.z = (uint)f2bf(b.x) | ((uint)f2bf(b.y) << 16);
  o.w = (uint)f2bf(b.z) | ((uint)f2bf(b.w) << 16);
  *(uint4*)(dst + i) = o;
}

// pack 4 weight matrices (Wq,Wk,Wv -> Wqkv concat; Wo -> Wobf)
__global__ __launch_bounds__(256) void pack_w4(
    const float* __restrict__ Wq, const float* __restrict__ Wk,
    const float* __restrict__ Wv, const float* __restrict__ Wo,
    ushort* __restrict__ Wqkv, ushort* __restrict__ Wobf) {
  constexpr int WSZ = 384 * 384;   // 147456
  int i = (blockIdx.x * 256 + threadIdx.x) * 8;   // 4*WSZ/8 threads = 288 blocks
  const float* src; ushort* dst; int off;
  if (i < WSZ)          { src = Wq; dst = Wqkv;           off = i; }
  else if (i < 2 * WSZ) { src = Wk; dst = Wqkv + WSZ;     off = i - WSZ; }
  else if (i < 3 * WSZ) { src = Wv; dst = Wqkv + 2 * WSZ; off = i - 2 * WSZ; }
  else                  { src = Wo; dst = Wobf;           off = i - 3 * WSZ; }
  float4 a = *(const float4*)(src + off);
  float4 b = *(const float4*)(src + off + 4);
  uint4 o;
  o.x = (uint)f2bf(a.x) | ((uint)f2bf(a.y) << 16);
  o.y = (uint)f2bf(a.z) | ((uint)f2bf(a.w) << 16);
  o.z = (uint)f2bf(b.x) | ((uint)f2bf(b.y) << 16);
  o.w = (uint)f2bf(b.z) | ((uint)f2bf(b.w) << 16);
  *(uint4*)(dst + off) = o;
}

// Fused QKV GEMM: C[4096 x 1152] = xbf * Wqkv^T, bf16 MFMA, 128x128 tiles.
// Cols 0..767 -> QKbf row-major bf16; cols 768..1151 -> Vt[b][h][dh][n] bf16.
__global__ __launch_bounds__(256) void gemm_qkv(
    const ushort* __restrict__ Abf, const ushort* __restrict__ Wbf,
    ushort* __restrict__ QKbf, ushort* __restrict__ Vt) {
  __shared__ ushort Asm[128 * 32];
  __shared__ ushort Bsm[128 * 32];
  const int tid = threadIdx.x, w = tid >> 6, lane = tid & 63;
  const int lq = lane & 15, g = lane >> 4;
  const int brow = blockIdx.y * 128, bcol = blockIdx.x * 128;
  const int wr0 = (w >> 1) * 64, wc0 = (w & 1) * 64;
  const int srow = lane >> 2, scol = (lane & 3) * 8;
  f32x4 acc[4][4];
#pragma unroll
  for (int mi = 0; mi < 4; ++mi)
#pragma unroll
    for (int ni = 0; ni < 4; ++ni) acc[mi][ni] = f32x4{0.f, 0.f, 0.f, 0.f};

  for (int kt = 0; kt < 384; kt += 32) {
    __syncthreads();
#pragma unroll
    for (int i = 0; i < 2; ++i) {
      int seg = w * 2 + i;   // wave-uniform
      gload16(Abf + (size_t)(brow + seg * 16 + srow) * 384 + kt + scol, Asm + seg * 512);
      gload16(Wbf + (size_t)(bcol + seg * 16 + srow) * 384 + kt + scol, Bsm + seg * 512);
    }
    __syncthreads();
    bf16x8 a[4], b[4];
#pragma unroll
    for (int mi = 0; mi < 4; ++mi)
      a[mi] = *(const bf16x8*)(Asm + (wr0 + mi * 16 + lq) * 32 + g * 8);
#pragma unroll
    for (int ni = 0; ni < 4; ++ni)
      b[ni] = *(const bf16x8*)(Bsm + (wc0 + ni * 16 + lq) * 32 + g * 8);
#pragma unroll
    for (int mi = 0; mi < 4; ++mi)
#pragma unroll
      for (int ni = 0; ni < 4; ++ni)
        acc[mi][ni] = __builtin_amdgcn_mfma_f32_16x16x32_bf16(a[mi], b[ni], acc[mi][ni], 0, 0, 0);
  }

  if (bcol < 768) {
#pragma unroll
    for (int mi = 0; mi < 4; ++mi)
#pragma unroll
      for (int ni = 0; ni < 4; ++ni)
#pragma unroll
        for (int r = 0; r < 4; ++r) {
          int row = brow + wr0 + mi * 16 + g * 4 + r;
          int col = bcol + wc0 + ni * 16 + lq;
          QKbf[(size_t)row * 768 + col] = f2bf(acc[mi][ni][r]);
        }
  } else {
#pragma unroll
    for (int mi = 0; mi < 4; ++mi)
#pragma unroll
      for (int ni = 0; ni < 4; ++ni)
#pragma unroll
        for (int r = 0; r < 4; ++r) {
          int row = brow + wr0 + mi * 16 + g * 4 + r;
          int vcol = bcol + wc0 + ni * 16 + lq - 768;
          int h = vcol / 48, dh = vcol - h * 48;
          int bb = row >> 11, nn = row & 2047;
          Vt[((size_t)(bb * H + h) * 48 + dh) * N + nn] = f2bf(acc[mi][ni][r]);
        }
  }
}

// Out-proj GEMM: C[4096 x 384] f32 = Obf * Wo^T, 64x128 tiles.
__global__ __launch_bounds__(256) void gemm_out(
    const ushort* __restrict__ Abf, const ushort* __restrict__ Wbf,
    float* __restrict__ Cout) {
  __shared__ ushort Asm[64 * 32];
  __shared__ ushort Bsm[128 * 32];
  const int tid = threadIdx.x, w = tid >> 6, lane = tid & 63;
  const int lq = lane & 15, g = lane >> 4;
  const int brow = blockIdx.y * 64, bcol = blockIdx.x * 128;
  const int wr0 = (w >> 1) * 32, wc0 = (w & 1) * 64;
  const int srow = lane >> 2, scol = (lane & 3) * 8;
  f32x4 acc[2][4];
#pragma unroll
  for (int mi = 0; mi < 2; ++mi)
#pragma unroll
    for (int ni = 0; ni < 4; ++ni) acc[mi][ni] = f32x4{0.f, 0.f, 0.f, 0.f};

  for (int kt = 0; kt < 384; kt += 32) {
    __syncthreads();
    gload16(Abf + (size_t)(brow + w * 16 + srow) * 384 + kt + scol, Asm + w * 512);
#pragma unroll
    for (int i = 0; i < 2; ++i) {
      int seg = w * 2 + i;
      gload16(Wbf + (size_t)(bcol + seg * 16 + srow) * 384 + kt + scol, Bsm + seg * 512);
    }
    __syncthreads();
    bf16x8 a[2], b[4];
#pragma unroll
    for (int mi = 0; mi < 2; ++mi)
      a[mi] = *(const bf16x8*)(Asm + (wr0 + mi * 16 + lq) * 32 + g * 8);
#pragma unroll
    for (int ni = 0; ni < 4; ++ni)
      b[ni] = *(const bf16x8*)(Bsm + (wc0 + ni * 16 + lq) * 32 + g * 8);
#pragma unroll
    for (int mi = 0; mi < 2; ++mi)
#pragma unroll
      for (int ni = 0; ni < 4; ++ni)
        acc[mi][ni] = __builtin_amdgcn_mfma_f32_16x16x32_bf16(a[mi], b[ni], acc[mi][ni], 0, 0, 0);
  }
#pragma unroll
  for (int mi = 0; mi < 2; ++mi)
#pragma unroll
    for (int ni = 0; ni < 4; ++ni)
#pragma unroll
      for (int r = 0; r < 4; ++r) {
        int row = brow + wr0 + mi * 16 + g * 4 + r;
        int col = bcol + wc0 + ni * 16 + lq;
        Cout[(size_t)row * 384 + col] = acc[mi][ni][r];
      }
}

// Rotate each 3-vector chunk by the node's frame, scale, repack bf16.
__global__ __launch_bounds__(256) void rotate_pack(
    const ushort* __restrict__ QK, const float* __restrict__ F,
    ushort* __restrict__ dst, int coff, float scale) {
  int idx = blockIdx.x * 256 + threadIdx.x;     // M*H*16
  int gq = idx & 15;
  int nh = idx >> 4;
  int h = nh & 7;
  int bn = nh >> 3;
  const ushort* s = QK + (size_t)bn * 768 + coff + h * 48 + gq * 3;
  const float* R = F + (size_t)bn * 9;
  float v0 = bf2f(s[0]), v1 = bf2f(s[1]), v2 = bf2f(s[2]);
  float w0 = (R[0] * v0 + R[1] * v1 + R[2] * v2) * scale;
  float w1 = (R[3] * v0 + R[4] * v1 + R[5] * v2) * scale;
  float w2 = (R[6] * v0 + R[7] * v1 + R[8] * v2) * scale;
  ushort* d = dst + (size_t)bn * 384 + h * 48 + gq * 3;
  d[0] = f2bf(w0); d[1] = f2bf(w1); d[2] = f2bf(w2);
}

// MFMA flash attention (as R3), epilogue writes bf16.
__global__ __launch_bounds__(256) void attn_mfma(
    const ushort* __restrict__ Qbf, const ushort* __restrict__ Kbf,
    const ushort* __restrict__ Vt, ushort* __restrict__ Obf) {
  __shared__ ushort K_lds[64][72];      // [key][dh padded 64->72], cols 48..63 zero
  __shared__ ushort V_lds[48][72];      // [dh][key padded]
  __shared__ ushort P_lds[4][16][72];   // per-wave [q][key padded]

  const int wg = (blockIdx.x & 7) * 64 + (blockIdx.x >> 3);  // XCD swizzle (512%8==0)
  const int qt = wg & 31;
  const int h = (wg >> 5) & 7;
  const int b = wg >> 8;
  const int tid = threadIdx.x;
  const int w = tid >> 6;
  const int lane = tid & 63;
  const int lq = lane & 15;
  const int g = lane >> 4;

  if (tid < 128) {               // zero K-dim padding (read by MFMA)
    int row = tid >> 1, c = tid & 1;
    *(uint4*)&K_lds[row][48 + c * 8] = make_uint4(0, 0, 0, 0);
  }

  bf16x8 qf0, qf1;
  {
    const ushort* qp = Qbf + (size_t)(b * N + qt * 64 + w * 16 + lq) * D + h * 48;
    qf0 = *(const bf16x8*)(qp + g * 8);
    if (g < 2) {
      qf1 = *(const bf16x8*)(qp + 32 + g * 8);
    } else {
      bf16x8 z = {0, 0, 0, 0, 0, 0, 0, 0};
      qf1 = z;
    }
  }

  float m = -3.0e38f, l = 0.f;
  f32x4 oacc[3];
#pragma unroll
  for (int d = 0; d < 3; ++d) oacc[d] = f32x4{0.f, 0.f, 0.f, 0.f};

  for (int kt = 0; kt < N; kt += 64) {
    __syncthreads();
    for (int e = tid; e < 384; e += 256) {        // K tile: 64 rows x 48 halves
      int row = e / 6, c = e - row * 6;
      *(uint4*)&K_lds[row][c * 8] =
          *(const uint4*)(Kbf + (size_t)(b * N + kt + row) * D + h * 48 + c * 8);
    }
    for (int e = tid; e < 384; e += 256) {        // V^T tile: 48 rows x 64 halves
      int row = e >> 3, c = e & 7;
      *(uint4*)&V_lds[row][c * 8] =
          *(const uint4*)(Vt + ((size_t)(b * H + h) * 48 + row) * (size_t)N + kt + c * 8);
    }
    __syncthreads();

    f32x4 st[4];
#pragma unroll
    for (int t = 0; t < 4; ++t) st[t] = f32x4{0.f, 0.f, 0.f, 0.f};
#pragma unroll
    for (int t = 0; t < 4; ++t) {
      bf16x8 a0 = *(const bf16x8*)&K_lds[t * 16 + lq][g * 8];
      st[t] = __builtin_amdgcn_mfma_f32_16x16x32_bf16(a0, qf0, st[t], 0, 0, 0);
      bf16x8 a1 = *(const bf16x8*)&K_lds[t * 16 + lq][32 + g * 8];
      st[t] = __builtin_amdgcn_mfma_f32_16x16x32_bf16(a1, qf1, st[t], 0, 0, 0);
    }

    float tmax = st[0][0];
#pragma unroll
    for (int t = 0; t < 4; ++t)
#pragma unroll
      for (int r = 0; r < 4; ++r) tmax = fmaxf(tmax, st[t][r]);
    tmax = fmaxf(tmax, __shfl_xor(tmax, 16));
    tmax = fmaxf(tmax, __shfl_xor(tmax, 32));
    float mnew = fmaxf(m, tmax);
    float corr = __expf(m - mnew);
    m = mnew;
    float psum = 0.f;
#pragma unroll
    for (int t = 0; t < 4; ++t) {
      ushort pb[4];
#pragma unroll
      for (int r = 0; r < 4; ++r) {
        float p = __expf(st[t][r] - mnew);
        psum += p;
        pb[r] = f2bf(p);
      }
      uint2 pk;
      pk.x = (uint)pb[0] | ((uint)pb[1] << 16);
      pk.y = (uint)pb[2] | ((uint)pb[3] << 16);
      *(uint2*)&P_lds[w][lq][t * 16 + g * 4] = pk;
    }
    psum += __shfl_xor(psum, 16);
    psum += __shfl_xor(psum, 32);
    l = l * corr + psum;

#pragma unroll
    for (int r = 0; r < 4; ++r) {
      float cr = __shfl(corr, g * 4 + r);
#pragma unroll
      for (int d = 0; d < 3; ++d) oacc[d][r] *= cr;
    }

#pragma unroll
    for (int ks = 0; ks < 2; ++ks) {
      bf16x8 pf = *(const bf16x8*)&P_lds[w][lq][ks * 32 + g * 8];
#pragma unroll
      for (int d = 0; d < 3; ++d) {
        bf16x8 vf = *(const bf16x8*)&V_lds[d * 16 + lq][ks * 32 + g * 8];
        oacc[d] = __builtin_amdgcn_mfma_f32_16x16x32_bf16(pf, vf, oacc[d], 0, 0, 0);
      }
    }
  }

  float linv = 1.f / l;
  float lr[4];
#pragma unroll
  for (int r = 0; r < 4; ++r) lr[r] = __shfl(linv, g * 4 + r);
#pragma unroll
  for (int d = 0; d < 3; ++d)
#pragma unroll
    for (int r = 0; r < 4; ++r)
      Obf[(size_t)(b * N + qt * 64 + w * 16 + g * 4 + r) * D + h * 48 + d * 16 + lq] =
          f2bf(oacc[d][r] * lr[r]);
}

// y = x + O + bo; LayerNorm(y)*gamma + beta -> out. O may alias out.
__global__ __launch_bounds__(384) void resid_ln(
    const float* __restrict__ x, const float* __restrict__ O,
    const float* __restrict__ bo, const float* __restrict__ gamma,
    const float* __restrict__ beta, float* __restrict__ out) {
  __shared__ float rs[6], rs2[6];
  __shared__ float smu, srstd;
  const int row = blockIdx.x;
  const int d = threadIdx.x;
  const size_t off = (size_t)row * D + d;
  float y = x[off] + O[off] + bo[d];
  float s = y, s2 = y * y;
#pragma unroll
  for (int o = 1; o < 64; o <<= 1) {
    s += __shfl_xor(s, o);
    s2 += __shfl_xor(s2, o);
  }
  const int wave = d >> 6, lane = d & 63;
  if (lane == 0) { rs[wave] = s; rs2[wave] = s2; }
  __syncthreads();
  if (d == 0) {
    float ts = 0.f, ts2 = 0.f;
#pragma unroll
    for (int wv = 0; wv < 6; ++wv) { ts += rs[wv]; ts2 += rs2[wv]; }
    float mu = ts / (float)D;
    float var = ts2 / (float)D - mu * mu;
    smu = mu;
    srstd = rsqrtf(var + EPS);
  }
  __syncthreads();
  out[off] = (y - smu) * srstd * gamma[d] + beta[d];
}

extern "C" void kernel_launch(void* const* d_in, const int* in_sizes, int n_in,
                              void* d_out, int out_size, void* d_ws, size_t ws_size,
                              hipStream_t stream) {
  const float* x      = (const float*)d_in[0];
  const float* frames = (const float*)d_in[1];
  const float* Wq     = (const float*)d_in[2];
  const float* Wk     = (const float*)d_in[3];
  const float* Wv     = (const float*)d_in[4];
  const float* Wo     = (const float*)d_in[5];
  const float* bo     = (const float*)d_in[6];
  const float* gamma  = (const float*)d_in[7];
  const float* beta   = (const float*)d_in[8];
  float* out = (float*)d_out;

  constexpr size_t WSZ = 384 * 384;
  ushort* xbf  = (ushort*)d_ws;                 // M*384 (dead after gemm_qkv)
  ushort* Obf  = xbf;                           // alias: attn output
  ushort* Wqkv = xbf + (size_t)M * 384;         // 1152*384
  ushort* Wobf = Wqkv + 3 * WSZ;                // 384*384
  ushort* QKbf = Wobf + WSZ;                    // M*768
  ushort* Qbf  = QKbf + (size_t)M * 768;        // M*384
  ushort* Kbf  = Qbf + (size_t)M * 384;         // M*384
  ushort* Vt   = Kbf + (size_t)M * 384;         // B*H*48*N

  const float qscale = 0.14433756729740643f;  // 1/sqrt(48)

  pack_bf16<<<M * D / (8 * 256), 256, 0, stream>>>(x, xbf);            // 768 blocks
  pack_w4<<<4 * WSZ / (8 * 256), 256, 0, stream>>>(Wq, Wk, Wv, Wo, Wqkv, Wobf);

  gemm_qkv<<<dim3(9, 32), 256, 0, stream>>>(xbf, Wqkv, QKbf, Vt);

  rotate_pack<<<M * H * 16 / 256, 256, 0, stream>>>(QKbf, frames, Qbf, 0, qscale);
  rotate_pack<<<M * H * 16 / 256, 256, 0, stream>>>(QKbf, frames, Kbf, 384, 1.0f);

  attn_mfma<<<B * H * (N / 64), 256, 0, stream>>>(Qbf, Kbf, Vt, Obf);

  gemm_out<<<dim3(3, 64), 256, 0, stream>>>(Obf, Wobf, out);
  resid_ln<<<M, D, 0, stream>>>(x, out, bo, gamma, beta, out);
}

// Round 5
// 91.127 us; speedup vs baseline: 13.6367x; 1.3334x over previous
//
#include <hip/hip_runtime.h>
#include <math.h>

constexpr int B = 2, N = 2048, D = 384, H = 8, Dh = 48;
constexpr int M = B * N;            // 4096 rows
constexpr float EPS = 1e-5f;
constexpr int WSZ = 384 * 384;

typedef short bf16x8 __attribute__((ext_vector_type(8)));
typedef float f32x4 __attribute__((ext_vector_type(4)));

#if __has_builtin(__builtin_amdgcn_exp2f)
#define EXP2(x) __builtin_amdgcn_exp2f(x)
#else
#define EXP2(x) exp2f(x)
#endif

__device__ __forceinline__ ushort f2bf(float f) {
  union { float f; uint u; } v; v.f = f;
  uint r = v.u + 0x7fffu + ((v.u >> 16) & 1u);   // RNE
  return (ushort)(r >> 16);
}
__device__ __forceinline__ float bf2f(ushort u) {
  union { uint u; float f; } v; v.u = ((uint)u) << 16;
  return v.f;
}

// async 16B global->LDS (dest: wave-uniform base + lane*16; src: per-lane)
__device__ __forceinline__ void gload16(const void* g, void* lds) {
  __builtin_amdgcn_global_load_lds(
      (const __attribute__((address_space(1))) unsigned int*)g,
      (__attribute__((address_space(3))) unsigned int*)lds, 16, 0, 0);
}

// Pack x and all 4 weights to bf16 in one kernel. 8 f32 per thread.
__global__ __launch_bounds__(256) void pack_all(
    const float* __restrict__ x, const float* __restrict__ Wq,
    const float* __restrict__ Wk, const float* __restrict__ Wv,
    const float* __restrict__ Wo, ushort* __restrict__ xbf,
    ushort* __restrict__ Wqkv, ushort* __restrict__ Wobf) {
  constexpr int XSZ = M * 384;
  int i = (blockIdx.x * 256 + threadIdx.x) * 8;
  const float* src; ushort* dst; int off;
  if (i < XSZ) { src = x; dst = xbf; off = i; }
  else {
    int j = i - XSZ;
    if (j < WSZ)          { src = Wq; dst = Wqkv;           off = j; }
    else if (j < 2 * WSZ) { src = Wk; dst = Wqkv + WSZ;     off = j - WSZ; }
    else if (j < 3 * WSZ) { src = Wv; dst = Wqkv + 2 * WSZ; off = j - 2 * WSZ; }
    else                  { src = Wo; dst = Wobf;           off = j - 3 * WSZ; }
  }
  float4 a = *(const float4*)(src + off);
  float4 b = *(const float4*)(src + off + 4);
  uint4 o;
  o.x = (uint)f2bf(a.x) | ((uint)f2bf(a.y) << 16);
  o.y = (uint)f2bf(a.z) | ((uint)f2bf(a.w) << 16);
  o.z = (uint)f2bf(b.x) | ((uint)f2bf(b.y) << 16);
  o.w = (uint)f2bf(b.z) | ((uint)f2bf(b.w) << 16);
  *(uint4*)(dst + off) = o;
}

// Fused QKV GEMM: [4096 x 1152] = xbf * Wqkv^T, bf16 MFMA, 128x128 tiles.
// Q cols -> Qpad[bn][h*64+dh], K cols -> Kpad (same layout), V -> Vt[b][h][dh][n].
__global__ __launch_bounds__(256) void gemm_qkv(
    const ushort* __restrict__ Abf, const ushort* __restrict__ Wbf,
    ushort* __restrict__ Qpad, ushort* __restrict__ Kpad,
    ushort* __restrict__ Vt) {
  __shared__ ushort Asm[128 * 32];
  __shared__ ushort Bsm[128 * 32];
  const int tid = threadIdx.x, w = tid >> 6, lane = tid & 63;
  const int lq = lane & 15, g = lane >> 4;
  const int brow = blockIdx.y * 128, bcol = blockIdx.x * 128;
  const int wr0 = (w >> 1) * 64, wc0 = (w & 1) * 64;
  const int srow = lane >> 2, scol = (lane & 3) * 8;
  f32x4 acc[4][4];
#pragma unroll
  for (int mi = 0; mi < 4; ++mi)
#pragma unroll
    for (int ni = 0; ni < 4; ++ni) acc[mi][ni] = f32x4{0.f, 0.f, 0.f, 0.f};

  for (int kt = 0; kt < 384; kt += 32) {
    __syncthreads();
#pragma unroll
    for (int i = 0; i < 2; ++i) {
      int seg = w * 2 + i;
      gload16(Abf + (size_t)(brow + seg * 16 + srow) * 384 + kt + scol, Asm + seg * 512);
      gload16(Wbf + (size_t)(bcol + seg * 16 + srow) * 384 + kt + scol, Bsm + seg * 512);
    }
    __syncthreads();
    bf16x8 a[4], b[4];
#pragma unroll
    for (int mi = 0; mi < 4; ++mi)
      a[mi] = *(const bf16x8*)(Asm + (wr0 + mi * 16 + lq) * 32 + g * 8);
#pragma unroll
    for (int ni = 0; ni < 4; ++ni)
      b[ni] = *(const bf16x8*)(Bsm + (wc0 + ni * 16 + lq) * 32 + g * 8);
#pragma unroll
    for (int mi = 0; mi < 4; ++mi)
#pragma unroll
      for (int ni = 0; ni < 4; ++ni)
        acc[mi][ni] = __builtin_amdgcn_mfma_f32_16x16x32_bf16(a[mi], b[ni], acc[mi][ni], 0, 0, 0);
  }

  if (bcol < 768) {
#pragma unroll
    for (int mi = 0; mi < 4; ++mi)
#pragma unroll
      for (int ni = 0; ni < 4; ++ni) {
        int colD = bcol + wc0 + ni * 16 + lq;
        ushort* dstm = (colD < 384) ? Qpad : Kpad;
        int c = (colD < 384) ? colD : colD - 384;
        int hh = c / 48, dh = c - hh * 48;
#pragma unroll
        for (int r = 0; r < 4; ++r) {
          int row = brow + wr0 + mi * 16 + g * 4 + r;
          dstm[(size_t)row * 512 + hh * 64 + dh] = f2bf(acc[mi][ni][r]);
        }
      }
  } else {
#pragma unroll
    for (int mi = 0; mi < 4; ++mi)
#pragma unroll
      for (int ni = 0; ni < 4; ++ni) {
        int vcol = bcol + wc0 + ni * 16 + lq - 768;
        int hh = vcol / 48, dh = vcol - hh * 48;
#pragma unroll
        for (int r = 0; r < 4; ++r) {
          int row = brow + wr0 + mi * 16 + g * 4 + r;
          int bb = row >> 11, nn = row & 2047;
          Vt[((size_t)(bb * H + hh) * 48 + dh) * N + nn] = f2bf(acc[mi][ni][r]);
        }
      }
  }
}

// In-place rotate 3-vector chunks of Qpad (scaled) and Kpad; zero pad halves 48..63.
__global__ __launch_bounds__(256) void rotate_both(
    ushort* __restrict__ Q, ushort* __restrict__ K,
    const float* __restrict__ F, float qscale) {
  constexpr int TOT = M * H * 16;
  int idx = blockIdx.x * 256 + threadIdx.x;   // 2*TOT threads
  ushort* T = (idx < TOT) ? Q : K;
  float scale = (idx < TOT) ? qscale : 1.0f;
  int rem = (idx < TOT) ? idx : idx - TOT;
  int gq = rem & 15;
  int nh = rem >> 4;
  int h = nh & 7;
  int bn = nh >> 3;
  ushort* p = T + (size_t)bn * 512 + h * 64;
  if (gq < 8) *(uint*)(p + 48 + gq * 2) = 0u;    // zero padding halves 48..63
  ushort* s = p + gq * 3;
  const float* R = F + (size_t)bn * 9;
  float v0 = bf2f(s[0]), v1 = bf2f(s[1]), v2 = bf2f(s[2]);
  float w0 = (R[0] * v0 + R[1] * v1 + R[2] * v2) * scale;
  float w1 = (R[3] * v0 + R[4] * v1 + R[5] * v2) * scale;
  float w2 = (R[6] * v0 + R[7] * v1 + R[8] * v2) * scale;
  s[0] = f2bf(w0); s[1] = f2bf(w1); s[2] = f2bf(w2);
}

// MFMA flash attention with double-buffered async staging + XOR-swizzled LDS
// + exp2 softmax + defer-max. One (b,h), 64 q rows per block, 64-key tiles.
__global__ __launch_bounds__(256) void attn_mfma(
    const ushort* __restrict__ Qpad, const ushort* __restrict__ Kpad,
    const ushort* __restrict__ Vt, ushort* __restrict__ Obf) {
  __shared__ ushort K_lds[2][64 * 64];   // [key][8 chunks of 8 halves], chunk^=(row&7)
  __shared__ ushort V_lds[2][48 * 64];   // [dh][8 key-chunks], swizzled
  __shared__ ushort P_lds[4][16 * 64];   // per-wave [q][8 key-chunks], swizzled

  const int wg = (blockIdx.x & 7) * 64 + (blockIdx.x >> 3);  // XCD swizzle
  const int qt = wg & 31;
  const int h = (wg >> 5) & 7;
  const int b = wg >> 8;
  const int tid = threadIdx.x;
  const int w = tid >> 6;
  const int lane = tid & 63;
  const int lq = lane & 15;
  const int g = lane >> 4;
  const int l7 = lq & 7;
  const int srow8 = lane >> 3;   // staging: row within 8-row segment
  const int sc = lane & 7;       // staging: physical chunk within row

  // Q fragments (halves 48..63 are zero in global)
  const ushort* qp = Qpad + (size_t)(b * N + qt * 64 + w * 16 + lq) * 512 + h * 64;
  bf16x8 qf0 = *(const bf16x8*)(qp + g * 8);
  bf16x8 qf1 = *(const bf16x8*)(qp + 32 + g * 8);

  const size_t kbase = (size_t)(b * N) * 512 + h * 64;
  const size_t vbase = ((size_t)(b * H + h) * 48) * (size_t)N;

  auto stage = [&](int buf, int kt) {
    // 14 wave-issues: 8 K segments (8 rows each), 6 V segments
    for (int s = w; s < 14; s += 4) {
      if (s < 8) {
        int row = s * 8 + srow8;
        int c = sc ^ (row & 7);          // inverse-swizzled global source
        gload16(Kpad + kbase + (size_t)(kt + row) * 512 + c * 8,
                &K_lds[buf][s * 512]);
      } else {
        int row = (s - 8) * 8 + srow8;
        int c = sc ^ (row & 7);
        gload16(Vt + vbase + (size_t)row * N + kt + c * 8,
                &V_lds[buf][(s - 8) * 512]);
      }
    }
  };

  float m = -3.0e38f, l = 0.f;
  f32x4 oacc[3];
#pragma unroll
  for (int d = 0; d < 3; ++d) oacc[d] = f32x4{0.f, 0.f, 0.f, 0.f};

  stage(0, 0);
  __syncthreads();
  int cur = 0;

  for (int t = 0; t < 32; ++t) {
    if (t < 31) stage(cur ^ 1, (t + 1) * 64);

    const ushort* Kc = K_lds[cur];
    const ushort* Vc = V_lds[cur];

    // S^T[key, q] = K * Q
    f32x4 st[4];
#pragma unroll
    for (int t4 = 0; t4 < 4; ++t4) st[t4] = f32x4{0.f, 0.f, 0.f, 0.f};
#pragma unroll
    for (int t4 = 0; t4 < 4; ++t4) {
      int row = t4 * 16 + lq;
      bf16x8 a0 = *(const bf16x8*)(Kc + row * 64 + ((g ^ l7) * 8));
      st[t4] = __builtin_amdgcn_mfma_f32_16x16x32_bf16(a0, qf0, st[t4], 0, 0, 0);
      bf16x8 a1 = *(const bf16x8*)(Kc + row * 64 + (((g ^ 4) ^ l7) * 8));
      st[t4] = __builtin_amdgcn_mfma_f32_16x16x32_bf16(a1, qf1, st[t4], 0, 0, 0);
    }

    // per-q tile max (4 lanes per q share via xor 16/32)
    float tmax = st[0][0];
#pragma unroll
    for (int t4 = 0; t4 < 4; ++t4)
#pragma unroll
      for (int r = 0; r < 4; ++r) tmax = fmaxf(tmax, st[t4][r]);
    tmax = fmaxf(tmax, __shfl_xor(tmax, 16));
    tmax = fmaxf(tmax, __shfl_xor(tmax, 32));

    // defer-max: only rescale when some q's max grew past threshold
    if (__ballot(tmax > m + 8.0f)) {
      float mnew = fmaxf(m, tmax);
      float corr = EXP2(m - mnew);
      m = mnew;
      l *= corr;
#pragma unroll
      for (int r = 0; r < 4; ++r) {
        float cr = __shfl(corr, g * 4 + r);
#pragma unroll
        for (int d = 0; d < 3; ++d) oacc[d][r] *= cr;
      }
    }

    float psum = 0.f;
#pragma unroll
    for (int t4 = 0; t4 < 4; ++t4) {
      ushort pb[4];
#pragma unroll
      for (int r = 0; r < 4; ++r) {
        float p = EXP2(st[t4][r] - m);
        psum += p;
        pb[r] = f2bf(p);
      }
      uint2 pk;
      pk.x = (uint)pb[0] | ((uint)pb[1] << 16);
      pk.y = (uint)pb[2] | ((uint)pb[3] << 16);
      *(uint2*)(P_lds[w] + lq * 64 + (((2 * t4 + (g >> 1)) ^ l7) * 8) + (g & 1) * 4) = pk;
    }
    psum += __shfl_xor(psum, 16);
    psum += __shfl_xor(psum, 32);
    l += psum;

    // PV: O[q,dh] += P * V^T
#pragma unroll
    for (int ks = 0; ks < 2; ++ks) {
      bf16x8 pf = *(const bf16x8*)(P_lds[w] + lq * 64 + ((((ks << 2) | g) ^ l7) * 8));
#pragma unroll
      for (int d = 0; d < 3; ++d) {
        bf16x8 vf = *(const bf16x8*)(Vc + (d * 16 + lq) * 64 + ((((ks << 2) | g) ^ l7) * 8));
        oacc[d] = __builtin_amdgcn_mfma_f32_16x16x32_bf16(pf, vf, oacc[d], 0, 0, 0);
      }
    }

    __syncthreads();   // drains staged loads for next tile; guards buffer reuse
    cur ^= 1;
  }

  float linv = 1.f / l;
  float lr[4];
#pragma unroll
  for (int r = 0; r < 4; ++r) lr[r] = __shfl(linv, g * 4 + r);
#pragma unroll
  for (int d = 0; d < 3; ++d)
#pragma unroll
    for (int r = 0; r < 4; ++r)
      Obf[(size_t)(b * N + qt * 64 + w * 16 + g * 4 + r) * D + h * 48 + d * 16 + lq] =
          f2bf(oacc[d][r] * lr[r]);
}

// Out-proj GEMM: C[4096 x 384] f32 = Obf * Wo^T, 64x128 tiles.
__global__ __launch_bounds__(256) void gemm_out(
    const ushort* __restrict__ Abf, const ushort* __restrict__ Wbf,
    float* __restrict__ Cout) {
  __shared__ ushort Asm[64 * 32];
  __shared__ ushort Bsm[128 * 32];
  const int tid = threadIdx.x, w = tid >> 6, lane = tid & 63;
  const int lq = lane & 15, g = lane >> 4;
  const int brow = blockIdx.y * 64, bcol = blockIdx.x * 128;
  const int wr0 = (w >> 1) * 32, wc0 = (w & 1) * 64;
  const int srow = lane >> 2, scol = (lane & 3) * 8;
  f32x4 acc[2][4];
#pragma unroll
  for (int mi = 0; mi < 2; ++mi)
#pragma unroll
    for (int ni = 0; ni < 4; ++ni) acc[mi][ni] = f32x4{0.f, 0.f, 0.f, 0.f};

  for (int kt = 0; kt < 384; kt += 32) {
    __syncthreads();
    gload16(Abf + (size_t)(brow + w * 16 + srow) * 384 + kt + scol, Asm + w * 512);
#pragma unroll
    for (int i = 0; i < 2; ++i) {
      int seg = w * 2 + i;
      gload16(Wbf + (size_t)(bcol + seg * 16 + srow) * 384 + kt + scol, Bsm + seg * 512);
    }
    __syncthreads();
    bf16x8 a[2], b[4];
#pragma unroll
    for (int mi = 0; mi < 2; ++mi)
      a[mi] = *(const bf16x8*)(Asm + (wr0 + mi * 16 + lq) * 32 + g * 8);
#pragma unroll
    for (int ni = 0; ni < 4; ++ni)
      b[ni] = *(const bf16x8*)(Bsm + (wc0 + ni * 16 + lq) * 32 + g * 8);
#pragma unroll
    for (int mi = 0; mi < 2; ++mi)
#pragma unroll
      for (int ni = 0; ni < 4; ++ni)
        acc[mi][ni] = __builtin_amdgcn_mfma_f32_16x16x32_bf16(a[mi], b[ni], acc[mi][ni], 0, 0, 0);
  }
#pragma unroll
  for (int mi = 0; mi < 2; ++mi)
#pragma unroll
    for (int ni = 0; ni < 4; ++ni)
#pragma unroll
      for (int r = 0; r < 4; ++r) {
        int row = brow + wr0 + mi * 16 + g * 4 + r;
        int col = bcol + wc0 + ni * 16 + lq;
        Cout[(size_t)row * 384 + col] = acc[mi][ni][r];
      }
}

// y = x + O + bo; LayerNorm(y)*gamma + beta -> out. O may alias out.
__global__ __launch_bounds__(384) void resid_ln(
    const float* __restrict__ x, const float* __restrict__ O,
    const float* __restrict__ bo, const float* __restrict__ gamma,
    const float* __restrict__ beta, float* __restrict__ out) {
  __shared__ float rs[6], rs2[6];
  __shared__ float smu, srstd;
  const int row = blockIdx.x;
  const int d = threadIdx.x;
  const size_t off = (size_t)row * D + d;
  float y = x[off] + O[off] + bo[d];
  float s = y, s2 = y * y;
#pragma unroll
  for (int o = 1; o < 64; o <<= 1) {
    s += __shfl_xor(s, o);
    s2 += __shfl_xor(s2, o);
  }
  const int wave = d >> 6, lane = d & 63;
  if (lane == 0) { rs[wave] = s; rs2[wave] = s2; }
  __syncthreads();
  if (d == 0) {
    float ts = 0.f, ts2 = 0.f;
#pragma unroll
    for (int wv = 0; wv < 6; ++wv) { ts += rs[wv]; ts2 += rs2[wv]; }
    float mu = ts / (float)D;
    float var = ts2 / (float)D - mu * mu;
    smu = mu;
    srstd = rsqrtf(var + EPS);
  }
  __syncthreads();
  out[off] = (y - smu) * srstd * gamma[d] + beta[d];
}

extern "C" void kernel_launch(void* const* d_in, const int* in_sizes, int n_in,
                              void* d_out, int out_size, void* d_ws, size_t ws_size,
                              hipStream_t stream) {
  const float* x      = (const float*)d_in[0];
  const float* frames = (const float*)d_in[1];
  const float* Wq     = (const float*)d_in[2];
  const float* Wk     = (const float*)d_in[3];
  const float* Wv     = (const float*)d_in[4];
  const float* Wo     = (const float*)d_in[5];
  const float* bo     = (const float*)d_in[6];
  const float* gamma  = (const float*)d_in[7];
  const float* beta   = (const float*)d_in[8];
  float* out = (float*)d_out;

  ushort* xbf  = (ushort*)d_ws;                 // M*384 (dead after gemm_qkv)
  ushort* Obf  = xbf;                           // alias: attn output
  ushort* Wqkv = xbf + (size_t)M * 384;         // 3*WSZ
  ushort* Wobf = Wqkv + 3 * (size_t)WSZ;        // WSZ
  ushort* Qpad = Wobf + (size_t)WSZ;            // M*512 (rows padded to 64/head)
  ushort* Kpad = Qpad + (size_t)M * 512;        // M*512
  ushort* Vt   = Kpad + (size_t)M * 512;        // B*H*48*N

  // 1/sqrt(48) * log2(e): fold softmax scale + exp2 conversion into Q
  const float qscale = 0.14433756729740643f * 1.4426950408889634f;

  pack_all<<<(M * 384 + 4 * WSZ) / (8 * 256), 256, 0, stream>>>(
      x, Wq, Wk, Wv, Wo, xbf, Wqkv, Wobf);

  gemm_qkv<<<dim3(9, 32), 256, 0, stream>>>(xbf, Wqkv, Qpad, Kpad, Vt);

  rotate_both<<<2 * M * H * 16 / 256, 256, 0, stream>>>(Qpad, Kpad, frames, qscale);

  attn_mfma<<<B * H * (N / 64), 256, 0, stream>>>(Qpad, Kpad, Vt, Obf);

  gemm_out<<<dim3(3, 64), 256, 0, stream>>>(Obf, Wobf, out);
  resid_ln<<<M, D, 0, stream>>>(x, out, bo, gamma, beta, out);
}

// Round 6
// 86.453 us; speedup vs baseline: 14.3739x; 1.0541x over previous
//
#include <hip/hip_runtime.h>
#include <hip/hip_bf16.h>
#include <math.h>

constexpr int B = 2, N = 2048, D = 384, H = 8, Dh = 48;
constexpr int M = B * N;            // 4096 rows
constexpr float EPS = 1e-5f;
constexpr int WSZ = 384 * 384;

typedef short bf16x8 __attribute__((ext_vector_type(8)));
typedef float f32x4 __attribute__((ext_vector_type(4)));

#if __has_builtin(__builtin_amdgcn_exp2f)
#define EXP2(x) __builtin_amdgcn_exp2f(x)
#else
#define EXP2(x) exp2f(x)
#endif

__device__ __forceinline__ ushort f2bf(float f) {
  union { float f; uint u; } v; v.f = f;
  uint r = v.u + 0x7fffu + ((v.u >> 16) & 1u);   // RNE
  return (ushort)(r >> 16);
}
__device__ __forceinline__ float bf2f(ushort u) {
  union { uint u; float f; } v; v.u = ((uint)u) << 16;
  return v.f;
}
// two f32 -> packed 2xbf16 (compiler emits v_cvt_pk_bf16_f32)
__device__ __forceinline__ uint pk_bf16(float lo, float hi) {
  union { __hip_bfloat162 h; uint u; } v;
  v.h = __float22bfloat162_rn(make_float2(lo, hi));
  return v.u;
}

// async 16B global->LDS (dest: wave-uniform base + lane*16; src: per-lane)
__device__ __forceinline__ void gload16(const void* g, void* lds) {
  __builtin_amdgcn_global_load_lds(
      (const __attribute__((address_space(1))) unsigned int*)g,
      (__attribute__((address_space(3))) unsigned int*)lds, 16, 0, 0);
}

// Pack x and all 4 weights to bf16 in one kernel. 8 f32 per thread.
__global__ __launch_bounds__(256) void pack_all(
    const float* __restrict__ x, const float* __restrict__ Wq,
    const float* __restrict__ Wk, const float* __restrict__ Wv,
    const float* __restrict__ Wo, ushort* __restrict__ xbf,
    ushort* __restrict__ Wqkv, ushort* __restrict__ Wobf) {
  constexpr int XSZ = M * 384;
  int i = (blockIdx.x * 256 + threadIdx.x) * 8;
  const float* src; ushort* dst; int off;
  if (i < XSZ) { src = x; dst = xbf; off = i; }
  else {
    int j = i - XSZ;
    if (j < WSZ)          { src = Wq; dst = Wqkv;           off = j; }
    else if (j < 2 * WSZ) { src = Wk; dst = Wqkv + WSZ;     off = j - WSZ; }
    else if (j < 3 * WSZ) { src = Wv; dst = Wqkv + 2 * WSZ; off = j - 2 * WSZ; }
    else                  { src = Wo; dst = Wobf;           off = j - 3 * WSZ; }
  }
  float4 a = *(const float4*)(src + off);
  float4 b = *(const float4*)(src + off + 4);
  uint4 o;
  o.x = pk_bf16(a.x, a.y);
  o.y = pk_bf16(a.z, a.w);
  o.z = pk_bf16(b.x, b.y);
  o.w = pk_bf16(b.z, b.w);
  *(uint4*)(dst + off) = o;
}

// Fused QKV GEMM: [4096 x 1152] = xbf * Wqkv^T, bf16 MFMA, 128x128 tiles.
// Q cols -> Qpad[bn][h*64+dh], K cols -> Kpad (same layout), V -> Vt[b][h][dh][n].
__global__ __launch_bounds__(256) void gemm_qkv(
    const ushort* __restrict__ Abf, const ushort* __restrict__ Wbf,
    ushort* __restrict__ Qpad, ushort* __restrict__ Kpad,
    ushort* __restrict__ Vt) {
  __shared__ ushort Asm[128 * 32];
  __shared__ ushort Bsm[128 * 32];
  const int tid = threadIdx.x, w = tid >> 6, lane = tid & 63;
  const int lq = lane & 15, g = lane >> 4;
  const int brow = blockIdx.y * 128, bcol = blockIdx.x * 128;
  const int wr0 = (w >> 1) * 64, wc0 = (w & 1) * 64;
  const int srow = lane >> 2, scol = (lane & 3) * 8;
  f32x4 acc[4][4];
#pragma unroll
  for (int mi = 0; mi < 4; ++mi)
#pragma unroll
    for (int ni = 0; ni < 4; ++ni) acc[mi][ni] = f32x4{0.f, 0.f, 0.f, 0.f};

  for (int kt = 0; kt < 384; kt += 32) {
    __syncthreads();
#pragma unroll
    for (int i = 0; i < 2; ++i) {
      int seg = w * 2 + i;
      gload16(Abf + (size_t)(brow + seg * 16 + srow) * 384 + kt + scol, Asm + seg * 512);
      gload16(Wbf + (size_t)(bcol + seg * 16 + srow) * 384 + kt + scol, Bsm + seg * 512);
    }
    __syncthreads();
    bf16x8 a[4], b[4];
#pragma unroll
    for (int mi = 0; mi < 4; ++mi)
      a[mi] = *(const bf16x8*)(Asm + (wr0 + mi * 16 + lq) * 32 + g * 8);
#pragma unroll
    for (int ni = 0; ni < 4; ++ni)
      b[ni] = *(const bf16x8*)(Bsm + (wc0 + ni * 16 + lq) * 32 + g * 8);
#pragma unroll
    for (int mi = 0; mi < 4; ++mi)
#pragma unroll
      for (int ni = 0; ni < 4; ++ni)
        acc[mi][ni] = __builtin_amdgcn_mfma_f32_16x16x32_bf16(a[mi], b[ni], acc[mi][ni], 0, 0, 0);
  }

  if (bcol < 768) {
#pragma unroll
    for (int mi = 0; mi < 4; ++mi)
#pragma unroll
      for (int ni = 0; ni < 4; ++ni) {
        int colD = bcol + wc0 + ni * 16 + lq;
        ushort* dstm = (colD < 384) ? Qpad : Kpad;
        int c = (colD < 384) ? colD : colD - 384;
        int hh = c / 48, dh = c - hh * 48;
#pragma unroll
        for (int r = 0; r < 4; ++r) {
          int row = brow + wr0 + mi * 16 + g * 4 + r;
          dstm[(size_t)row * 512 + hh * 64 + dh] = f2bf(acc[mi][ni][r]);
        }
      }
  } else {
#pragma unroll
    for (int mi = 0; mi < 4; ++mi)
#pragma unroll
      for (int ni = 0; ni < 4; ++ni) {
        int vcol = bcol + wc0 + ni * 16 + lq - 768;
        int hh = vcol / 48, dh = vcol - hh * 48;
#pragma unroll
        for (int r = 0; r < 4; ++r) {
          int row = brow + wr0 + mi * 16 + g * 4 + r;
          int bb = row >> 11, nn = row & 2047;
          Vt[((size_t)(bb * H + hh) * 48 + dh) * N + nn] = f2bf(acc[mi][ni][r]);
        }
      }
  }
}

// In-place rotate 3-vector chunks of Qpad (scaled) and Kpad; zero pad halves 48..63.
__global__ __launch_bounds__(256) void rotate_both(
    ushort* __restrict__ Q, ushort* __restrict__ K,
    const float* __restrict__ F, float qscale) {
  constexpr int TOT = M * H * 16;
  int idx = blockIdx.x * 256 + threadIdx.x;   // 2*TOT threads
  ushort* T = (idx < TOT) ? Q : K;
  float scale = (idx < TOT) ? qscale : 1.0f;
  int rem = (idx < TOT) ? idx : idx - TOT;
  int gq = rem & 15;
  int nh = rem >> 4;
  int h = nh & 7;
  int bn = nh >> 3;
  ushort* p = T + (size_t)bn * 512 + h * 64;
  if (gq < 8) *(uint*)(p + 48 + gq * 2) = 0u;    // zero padding halves 48..63
  ushort* s = p + gq * 3;
  const float* R = F + (size_t)bn * 9;
  float v0 = bf2f(s[0]), v1 = bf2f(s[1]), v2 = bf2f(s[2]);
  float w0 = (R[0] * v0 + R[1] * v1 + R[2] * v2) * scale;
  float w1 = (R[3] * v0 + R[4] * v1 + R[5] * v2) * scale;
  float w2 = (R[6] * v0 + R[7] * v1 + R[8] * v2) * scale;
  s[0] = f2bf(w0); s[1] = f2bf(w1); s[2] = f2bf(w2);
}

// Split-K MFMA flash attention. Block = (half,b,h,qt): 64 q rows (4 waves x16),
// keys [half*1024, half*1024+1024). Writes unnormalized bf16 acc + f32 (m,l).
__global__ __launch_bounds__(256) void attn_mfma(
    const ushort* __restrict__ Qpad, const ushort* __restrict__ Kpad,
    const ushort* __restrict__ Vt, ushort* __restrict__ Pacc,
    float* __restrict__ Pml) {
  __shared__ ushort K_lds[2][64 * 64];   // [key][8 chunks of 8 halves], chunk^=(row&7)
  __shared__ ushort V_lds[2][48 * 64];   // [dh][8 key-chunks], swizzled
  __shared__ ushort P_lds[4][16 * 64];   // per-wave [q][8 key-chunks], swizzled

  const int bid = blockIdx.x;
  const int wg = (bid & 7) * 128 + (bid >> 3);  // XCD swizzle (1024 = 8*128)
  const int qt = wg & 31;
  const int rest = wg >> 5;
  const int h = rest & 7;
  const int b = (rest >> 3) & 1;
  const int half = rest >> 4;
  const int kt0 = half * 1024;
  const int tid = threadIdx.x;
  const int w = tid >> 6;
  const int lane = tid & 63;
  const int lq = lane & 15;
  const int g = lane >> 4;
  const int l7 = lq & 7;
  const int srow8 = lane >> 3;   // staging: row within 8-row segment
  const int csw = (lane & 7) ^ srow8;  // staging: inverse-swizzled chunk (const/lane)

  // Q fragments (halves 48..63 are zero in global)
  const ushort* qp = Qpad + (size_t)(b * N + qt * 64 + w * 16 + lq) * 512 + h * 64;
  bf16x8 qf0 = *(const bf16x8*)(qp + g * 8);
  bf16x8 qf1 = *(const bf16x8*)(qp + 32 + g * 8);

  // staging pointers (advance by constants each tile)
  const ushort* kg0 = Kpad + (size_t)(b * N) * 512 + h * 64
                    + (size_t)(kt0 + w * 8 + srow8) * 512 + csw * 8;
  const ushort* kg1 = kg0 + 32 * 512;
  const ushort* vg0 = Vt + ((size_t)(b * H + h) * 48 + w * 8 + srow8) * (size_t)N
                    + kt0 + csw * 8;
  const ushort* vg1 = vg0 + 32 * (size_t)N;   // used only when w<2

  auto stage = [&](int buf) {
    gload16(kg0, &K_lds[buf][w * 512]);
    gload16(kg1, &K_lds[buf][(w + 4) * 512]);
    gload16(vg0, &V_lds[buf][w * 512]);
    if (w < 2) gload16(vg1, &V_lds[buf][(w + 4) * 512]);
    kg0 += 64 * 512; kg1 += 64 * 512; vg0 += 64; vg1 += 64;
  };

  float m = -3.0e38f, l = 0.f;
  f32x4 oacc[3];
#pragma unroll
  for (int d = 0; d < 3; ++d) oacc[d] = f32x4{0.f, 0.f, 0.f, 0.f};

  stage(0);
  __syncthreads();
  int cur = 0;

  for (int t = 0; t < 16; ++t) {
    if (t < 15) stage(cur ^ 1);

    const ushort* Kc = K_lds[cur];
    const ushort* Vc = V_lds[cur];

    // S^T[key, q] = K * Q
    f32x4 st[4];
#pragma unroll
    for (int t4 = 0; t4 < 4; ++t4) st[t4] = f32x4{0.f, 0.f, 0.f, 0.f};
#pragma unroll
    for (int t4 = 0; t4 < 4; ++t4) {
      int row = t4 * 16 + lq;
      bf16x8 a0 = *(const bf16x8*)(Kc + row * 64 + ((g ^ l7) * 8));
      st[t4] = __builtin_amdgcn_mfma_f32_16x16x32_bf16(a0, qf0, st[t4], 0, 0, 0);
      bf16x8 a1 = *(const bf16x8*)(Kc + row * 64 + (((g ^ 4) ^ l7) * 8));
      st[t4] = __builtin_amdgcn_mfma_f32_16x16x32_bf16(a1, qf1, st[t4], 0, 0, 0);
    }

    // per-q tile max (4 lanes per q share via xor 16/32)
    float tmax = st[0][0];
#pragma unroll
    for (int t4 = 0; t4 < 4; ++t4)
#pragma unroll
      for (int r = 0; r < 4; ++r) tmax = fmaxf(tmax, st[t4][r]);
    tmax = fmaxf(tmax, __shfl_xor(tmax, 16));
    tmax = fmaxf(tmax, __shfl_xor(tmax, 32));

    // defer-max: only rescale when some q's max grew past threshold
    if (__ballot(tmax > m + 8.0f)) {
      float mnew = fmaxf(m, tmax);
      float corr = EXP2(m - mnew);
      m = mnew;
      l *= corr;
#pragma unroll
      for (int r = 0; r < 4; ++r) {
        float cr = __shfl(corr, g * 4 + r);
#pragma unroll
        for (int d = 0; d < 3; ++d) oacc[d][r] *= cr;
      }
    }

    float psum = 0.f;
#pragma unroll
    for (int t4 = 0; t4 < 4; ++t4) {
      float p0 = EXP2(st[t4][0] - m);
      float p1 = EXP2(st[t4][1] - m);
      float p2 = EXP2(st[t4][2] - m);
      float p3 = EXP2(st[t4][3] - m);
      psum += (p0 + p1) + (p2 + p3);
      uint2 pk;
      pk.x = pk_bf16(p0, p1);
      pk.y = pk_bf16(p2, p3);
      *(uint2*)(P_lds[w] + lq * 64 + (((2 * t4 + (g >> 1)) ^ l7) * 8) + (g & 1) * 4) = pk;
    }
    psum += __shfl_xor(psum, 16);
    psum += __shfl_xor(psum, 32);
    l += psum;

    // PV: O[q,dh] += P * V^T
#pragma unroll
    for (int ks = 0; ks < 2; ++ks) {
      bf16x8 pf = *(const bf16x8*)(P_lds[w] + lq * 64 + ((((ks << 2) | g) ^ l7) * 8));
#pragma unroll
      for (int d = 0; d < 3; ++d) {
        bf16x8 vf = *(const bf16x8*)(Vc + (d * 16 + lq) * 64 + ((((ks << 2) | g) ^ l7) * 8));
        oacc[d] = __builtin_amdgcn_mfma_f32_16x16x32_bf16(pf, vf, oacc[d], 0, 0, 0);
      }
    }

    __syncthreads();   // drains staged loads for next tile; guards buffer reuse
    cur ^= 1;
  }

  // write partials: rows of this (half,b,h): PR = ((half*B+b)*H+h)*N + q
  const size_t pr0 = ((size_t)((half * B + b) * H + h)) * N + qt * 64 + w * 16;
#pragma unroll
  for (int d = 0; d < 3; ++d)
#pragma unroll
    for (int r = 0; r < 4; ++r)
      Pacc[(pr0 + g * 4 + r) * 48 + d * 16 + lq] = f2bf(oacc[d][r]);
  if (g == 0) {
    Pml[(pr0 + lq) * 2] = m;
    Pml[(pr0 + lq) * 2 + 1] = l;
  }
}

// Merge two split-K halves -> normalized bf16 O [M x 384].
__global__ __launch_bounds__(256) void attn_merge(
    const ushort* __restrict__ Pacc, const float* __restrict__ Pml,
    ushort* __restrict__ Obf) {
  int idx = blockIdx.x * 256 + threadIdx.x;   // 32768 = M*H
  int h = idx & 7, bn = idx >> 3;
  int b = bn >> 11, n = bn & 2047;
  size_t r0 = ((size_t)(b * H + h)) * N + n;            // half 0
  size_t r1 = ((size_t)((B + b) * H + h)) * N + n;      // half 1
  float m0 = Pml[r0 * 2], l0 = Pml[r0 * 2 + 1];
  float m1 = Pml[r1 * 2], l1 = Pml[r1 * 2 + 1];
  float mm = fmaxf(m0, m1);
  float w0 = EXP2(m0 - mm), w1 = EXP2(m1 - mm);
  float inv = 1.f / (l0 * w0 + l1 * w1);
  w0 *= inv; w1 *= inv;
  const ushort* p0 = Pacc + r0 * 48;
  const ushort* p1 = Pacc + r1 * 48;
  ushort* ob = Obf + (size_t)bn * 384 + h * 48;
#pragma unroll
  for (int j = 0; j < 6; ++j) {
    uint4 a = *(const uint4*)(p0 + j * 8);
    uint4 c = *(const uint4*)(p1 + j * 8);
    uint4 o;
    o.x = pk_bf16(bf2f((ushort)a.x) * w0 + bf2f((ushort)c.x) * w1,
                  bf2f((ushort)(a.x >> 16)) * w0 + bf2f((ushort)(c.x >> 16)) * w1);
    o.y = pk_bf16(bf2f((ushort)a.y) * w0 + bf2f((ushort)c.y) * w1,
                  bf2f((ushort)(a.y >> 16)) * w0 + bf2f((ushort)(c.y >> 16)) * w1);
    o.z = pk_bf16(bf2f((ushort)a.z) * w0 + bf2f((ushort)c.z) * w1,
                  bf2f((ushort)(a.z >> 16)) * w0 + bf2f((ushort)(c.z >> 16)) * w1);
    o.w = pk_bf16(bf2f((ushort)a.w) * w0 + bf2f((ushort)c.w) * w1,
                  bf2f((ushort)(a.w >> 16)) * w0 + bf2f((ushort)(c.w >> 16)) * w1);
    *(uint4*)(ob + j * 8) = o;
  }
}

// Fused out-proj + residual + LayerNorm. Block = 64 rows x all 384 cols.
__global__ __launch_bounds__(256) void gemm_out_ln(
    const ushort* __restrict__ Abf, const ushort* __restrict__ Wbf,
    const float* __restrict__ x, const float* __restrict__ bo,
    const float* __restrict__ gamma, const float* __restrict__ beta,
    float* __restrict__ out) {
  __shared__ ushort Asm[64 * 32];    // 4KB
  __shared__ ushort Bsm[384 * 32];   // 24KB
  const int tid = threadIdx.x, w = tid >> 6, lane = tid & 63;
  const int lq = lane & 15, g = lane >> 4;
  const int brow = blockIdx.x * 64;
  const int srow = lane >> 2, scol = (lane & 3) * 8;
  f32x4 acc[24];
#pragma unroll
  for (int ni = 0; ni < 24; ++ni) acc[ni] = f32x4{0.f, 0.f, 0.f, 0.f};

  for (int kt = 0; kt < 384; kt += 32) {
    __syncthreads();
    gload16(Abf + (size_t)(brow + w * 16 + srow) * 384 + kt + scol, Asm + w * 512);
#pragma unroll
    for (int i = 0; i < 6; ++i) {
      int seg = w * 6 + i;
      gload16(Wbf + (size_t)(seg * 16 + srow) * 384 + kt + scol, Bsm + seg * 512);
    }
    __syncthreads();
    bf16x8 a = *(const bf16x8*)(Asm + (w * 16 + lq) * 32 + g * 8);
#pragma unroll
    for (int ni = 0; ni < 24; ++ni) {
      bf16x8 bfr = *(const bf16x8*)(Bsm + (ni * 16 + lq) * 32 + g * 8);
      acc[ni] = __builtin_amdgcn_mfma_f32_16x16x32_bf16(a, bfr, acc[ni], 0, 0, 0);
    }
  }

  const int row0 = brow + w * 16 + g * 4;
#pragma unroll
  for (int r = 0; r < 4; ++r) {
    const float* xr = x + (size_t)(row0 + r) * 384;
    float s = 0.f, s2 = 0.f;
#pragma unroll
    for (int ni = 0; ni < 24; ++ni) {
      int col = ni * 16 + lq;
      float y = acc[ni][r] + xr[col] + bo[col];
      acc[ni][r] = y;
      s += y; s2 += y * y;
    }
#pragma unroll
    for (int o = 1; o < 16; o <<= 1) {
      s += __shfl_xor(s, o);
      s2 += __shfl_xor(s2, o);
    }
    float mu = s * (1.f / 384.f);
    float var = s2 * (1.f / 384.f) - mu * mu;
    float rstd = rsqrtf(var + EPS);
    float* orow = out + (size_t)(row0 + r) * 384;
#pragma unroll
    for (int ni = 0; ni < 24; ++ni) {
      int col = ni * 16 + lq;
      orow[col] = (acc[ni][r] - mu) * rstd * gamma[col] + beta[col];
    }
  }
}

extern "C" void kernel_launch(void* const* d_in, const int* in_sizes, int n_in,
                              void* d_out, int out_size, void* d_ws, size_t ws_size,
                              hipStream_t stream) {
  const float* x      = (const float*)d_in[0];
  const float* frames = (const float*)d_in[1];
  const float* Wq     = (const float*)d_in[2];
  const float* Wk     = (const float*)d_in[3];
  const float* Wv     = (const float*)d_in[4];
  const float* Wo     = (const float*)d_in[5];
  const float* bo     = (const float*)d_in[6];
  const float* gamma  = (const float*)d_in[7];
  const float* beta   = (const float*)d_in[8];
  float* out = (float*)d_out;

  ushort* xbf  = (ushort*)d_ws;                 // M*384 (dead after gemm_qkv)
  ushort* Obf  = xbf;                           // alias: merged attn output
  ushort* Wqkv = xbf + (size_t)M * 384;         // 3*WSZ
  ushort* Wobf = Wqkv + 3 * (size_t)WSZ;        // WSZ
  ushort* Qpad = Wobf + (size_t)WSZ;            // M*512
  ushort* Kpad = Qpad + (size_t)M * 512;        // M*512
  ushort* Vt   = Kpad + (size_t)M * 512;        // M*384
  ushort* Pacc = Vt + (size_t)M * 384;          // 2*B*H*N*48 bf16 (6.3MB)
  float*  Pml  = (float*)(Pacc + (size_t)2 * B * H * N * 48);  // 2*B*H*N*2 f32

  // 1/sqrt(48) * log2(e): fold softmax scale + exp2 conversion into Q
  const float qscale = 0.14433756729740643f * 1.4426950408889634f;

  pack_all<<<(M * 384 + 4 * WSZ) / (8 * 256), 256, 0, stream>>>(
      x, Wq, Wk, Wv, Wo, xbf, Wqkv, Wobf);

  gemm_qkv<<<dim3(9, 32), 256, 0, stream>>>(xbf, Wqkv, Qpad, Kpad, Vt);

  rotate_both<<<2 * M * H * 16 / 256, 256, 0, stream>>>(Qpad, Kpad, frames, qscale);

  attn_mfma<<<2 * B * H * (N / 64), 256, 0, stream>>>(Qpad, Kpad, Vt, Pacc, Pml);

  attn_merge<<<M * H / 256, 256, 0, stream>>>(Pacc, Pml, Obf);

  gemm_out_ln<<<M / 64, 256, 0, stream>>>(Obf, Wobf, x, bo, gamma, beta, out);
}